// Round 1
// 9856.609 us; speedup vs baseline: 1.5859x; 1.5859x over previous
//
#include <hip/hip_runtime.h>
#include <math.h>

// Problem constants
#define NB   2048   // batch
#define SEQ  64
#define CIN  142
#define DM   256
#define NH   8
#define DHD  32
#define FFD  512
#define NL   3
#define ED   128
#define KCB  1024
#define TT   65     // SEQ+1 (cls prepended)
#define NT   512    // threads per block

typedef __attribute__((ext_vector_type(4))) float f32x4;
typedef __attribute__((ext_vector_type(8))) _Float16 f16x8;
typedef __attribute__((ext_vector_type(4))) _Float16 f16x4;

// ---- split-fp16 GEMM (R9): x = hi + lo*2^-11, both fp16. lo is stored
// pre-scaled by 2^11 so it stays in fp16 normal range (weights ~0.02 would
// otherwise make lo denormal -> possible MFMA flush). Cross terms go to a
// second f32 accumulator, rescaled once at write-out:
//   C = Ahi*Bhi + (Ahi*Blo' + Alo'*Bhi) * 2^-11          (lo*lo ~2^-22, dropped)
// => ~fp32-quality product; attention/softmax/LN/VQ/head remain exact fp32.
#define LO_SCALE 2048.0f
#define LO_INV   (1.0f / 2048.0f)

// staging regions inside scr (offsets in halves):
//   stA hi/lo: [80][32]  (T up to 65, padded to 5 row-tiles of 16)
//   stB hi/lo: [128][32] (one 128-col O-pass)
// end = 13312 halves = 26624 B <= scr (6768 floats = 27072 B).
// Row pitch 32 halves = 64 B -> frag b128 reads & staging b64 writes are
// bank-uniform (even rows banks 0-15, odd rows 16-31).
#define ST_AHI 0
#define ST_ALO 2560
#define ST_BHI 5120
#define ST_BLO 9216

__device__ __forceinline__ float gelu_f(float x) {
  return 0.5f * x * (1.0f + erff(x * 0.70710678118654752f));
}

__device__ __forceinline__ float wave_bsum(float v) {
#pragma unroll
  for (int off = 32; off >= 1; off >>= 1) v += __shfl_xor(v, off, 64);
  return v;
}
__device__ __forceinline__ float wave_bmax(float v) {
#pragma unroll
  for (int off = 32; off >= 1; off >>= 1) v = fmaxf(v, __shfl_xor(v, off, 64));
  return v;
}

__device__ __forceinline__ void split4(float4 v, f16x4& hi, f16x4& lo) {
  _Float16 h0 = (_Float16)v.x, h1 = (_Float16)v.y,
           h2 = (_Float16)v.z, h3 = (_Float16)v.w;
  f16x4 h = {h0, h1, h2, h3};
  f16x4 l = {(_Float16)((v.x - (float)h0) * LO_SCALE),
             (_Float16)((v.y - (float)h1) * LO_SCALE),
             (_Float16)((v.z - (float)h2) * LO_SCALE),
             (_Float16)((v.w - (float)h3) * LO_SCALE)};
  hi = h;
  lo = l;
}

// ---------- MFMA GEMM: C[T x 16*NCT] (+)= A[T x K] * W[rows, K]^T ----------
// A: fp32 in LDS (pitch sldA), rows < tRows (rows beyond are zero-padded at
// stage time). W: fp32 global, staged row r -> grow = rbase + (r&31) + rsel*(r>>5)
// (rsel=32 contiguous; rsel=256 for per-head qkv q/k/v row gather).
// Per k-chunk of 32: stage split-fp16 A+B into scr, then wave w (< NCT) does
// col-tile w, RT row-tiles, 3 MFMAs each (v_mfma_f32_16x16x32_f16).
// Fragment addressing: lane holds row/col (lane&15), k = (lane>>4)*8 + j  ->
// one 16 B b128 per fragment; any k-permutation cancels since A and B use
// identical addressing. D layout (m89-verified): row=(lane>>4)*4+reg, col=lane&15.
template <int RT, int NCT>
__device__ __forceinline__ void mfma_gemm(
    f32x4* acc1, f32x4* acc2,
    const float* __restrict__ Wg, int wld, int rbase, int rsel, int orows,
    const float* srcA, int sldA, int tRows, int kdim, int kvalid,
    _Float16* stg, int tid, int wave, int lane) {
  _Float16* stAhi = stg + ST_AHI;
  _Float16* stAlo = stg + ST_ALO;
  _Float16* stBhi = stg + ST_BHI;
  _Float16* stBlo = stg + ST_BLO;
  const int q4 = lane >> 4, cl = lane & 15;
  const bool fastW = ((wld & 3) == 0);  // false only for embed (wld=142)
  for (int kc = 0; kc < kdim; kc += 32) {
    __syncthreads();  // staging buffers free (prev consumers done)
    // ---- stage A chunk: RT*16 rows x 32 cols (zero pad rows >= tRows) ----
    for (int f = tid; f < RT * 128; f += NT) {
      int r = f >> 3, c4 = (f & 7) << 2;
      float4 v = make_float4(0.f, 0.f, 0.f, 0.f);
      if (r < tRows) v = *(const float4*)&srcA[r * sldA + kc + c4];
      f16x4 hi, lo;
      split4(v, hi, lo);
      *(f16x4*)&stAhi[r * 32 + c4] = hi;
      *(f16x4*)&stAlo[r * 32 + c4] = lo;
    }
    // ---- stage B chunk: orows x 32 from global W (convert on the fly) ----
    const bool wfull = fastW && (kc + 32 <= kvalid);
    for (int f = tid; f < orows * 8; f += NT) {
      int r = f >> 3, c4 = (f & 7) << 2;
      int grow = rbase + (r & 31) + rsel * (r >> 5);
      float4 v;
      if (wfull) {
        v = *(const float4*)&Wg[grow * wld + kc + c4];
      } else {  // embed tail / unaligned wld: guarded scalar loads
        int cb = kc + c4;
        v.x = (cb < kvalid) ? Wg[grow * wld + cb] : 0.f;
        v.y = (cb + 1 < kvalid) ? Wg[grow * wld + cb + 1] : 0.f;
        v.z = (cb + 2 < kvalid) ? Wg[grow * wld + cb + 2] : 0.f;
        v.w = (cb + 3 < kvalid) ? Wg[grow * wld + cb + 3] : 0.f;
      }
      f16x4 hi, lo;
      split4(v, hi, lo);
      *(f16x4*)&stBhi[r * 32 + c4] = hi;
      *(f16x4*)&stBlo[r * 32 + c4] = lo;
    }
    __syncthreads();  // staging ready
    if (NCT == 8 || wave < NCT) {
      const int bof = (16 * wave + cl) * 32 + q4 * 8;
      f16x8 bh = *(const f16x8*)&stBhi[bof];
      f16x8 bl = *(const f16x8*)&stBlo[bof];
#pragma unroll
      for (int rt = 0; rt < RT; ++rt) {
        const int aof = (16 * rt + cl) * 32 + q4 * 8;
        f16x8 ah = *(const f16x8*)&stAhi[aof];
        f16x8 al = *(const f16x8*)&stAlo[aof];
        acc1[rt] = __builtin_amdgcn_mfma_f32_16x16x32_f16(ah, bh, acc1[rt], 0, 0, 0);
        acc2[rt] = __builtin_amdgcn_mfma_f32_16x16x32_f16(ah, bl, acc2[rt], 0, 0, 0);
        acc2[rt] = __builtin_amdgcn_mfma_f32_16x16x32_f16(al, bh, acc2[rt], 0, 0, 0);
      }
    }
  }
}

__device__ __forceinline__ void ln_rows(float* buf, const float* g, const float* be,
                                        int wave, int lane) {
  for (int t = wave; t < TT; t += 8) {
    float v0 = buf[t * DM + lane],       v1 = buf[t * DM + lane + 64];
    float v2 = buf[t * DM + lane + 128], v3 = buf[t * DM + lane + 192];
    float m = wave_bsum(v0 + v1 + v2 + v3) * (1.0f / 256.0f);
    float d0 = v0 - m, d1 = v1 - m, d2 = v2 - m, d3 = v3 - m;
    float var = wave_bsum(d0 * d0 + d1 * d1 + d2 * d2 + d3 * d3) * (1.0f / 256.0f);
    float rstd = 1.0f / sqrtf(var + 1e-5f);
    buf[t * DM + lane]       = d0 * rstd * g[lane]       + be[lane];
    buf[t * DM + lane + 64]  = d1 * rstd * g[lane + 64]  + be[lane + 64];
    buf[t * DM + lane + 128] = d2 * rstd * g[lane + 128] + be[lane + 128];
    buf[t * DM + lane + 192] = d3 * rstd * g[lane + 192] + be[lane + 192];
  }
}

// FF for one T-pass (rows [r0, r0+nr)): f1 = gelu(h@W1^T+b1) -> obuf [nr][512],
// then h[r0..] += f1@W2^T + b2. RTF = row-tiles (2 for nr=32, 3 for nr=33).
template <int RTF>
__device__ __forceinline__ void ff_block(int r0, int nr,
                                         const float* __restrict__ W1_l,
                                         const float* __restrict__ b1_l,
                                         const float* __restrict__ W2_l,
                                         const float* __restrict__ b2_l,
                                         float* hbuf, float* obuf, _Float16* stg,
                                         int tid, int wave, int lane) {
  const int q4 = lane >> 4, cl = lane & 15;
  const f32x4 Z4 = {0.f, 0.f, 0.f, 0.f};
  for (int oc = 0; oc < 4; ++oc) {  // FF1: 4 x 128-col passes
    f32x4 a1[RTF], a2[RTF];
#pragma unroll
    for (int i = 0; i < RTF; ++i) { a1[i] = Z4; a2[i] = Z4; }
    mfma_gemm<RTF, 8>(a1, a2, W1_l, DM, oc * 128, 32, 128,
                      hbuf + r0 * DM, DM, nr, DM, DM, stg, tid, wave, lane);
    int m = oc * 128 + wave * 16 + cl;
    float bias = b1_l[m];
#pragma unroll
    for (int rt = 0; rt < RTF; ++rt)
#pragma unroll
      for (int rg = 0; rg < 4; ++rg) {
        int t = rt * 16 + q4 * 4 + rg;
        if (t < nr) obuf[t * FFD + m] = gelu_f(a1[rt][rg] + a2[rt][rg] * LO_INV + bias);
      }
  }
  for (int oc = 0; oc < 2; ++oc) {  // FF2: K=512, 2 x 128-col passes
    f32x4 a1[RTF], a2[RTF];
#pragma unroll
    for (int i = 0; i < RTF; ++i) { a1[i] = Z4; a2[i] = Z4; }
    mfma_gemm<RTF, 8>(a1, a2, W2_l, FFD, oc * 128, 32, 128,
                      obuf, FFD, nr, FFD, FFD, stg, tid, wave, lane);
    int d = oc * 128 + wave * 16 + cl;
    float bias = b2_l[d];
#pragma unroll
    for (int rt = 0; rt < RTF; ++rt)
#pragma unroll
      for (int rg = 0; rg < 4; ++rg) {
        int t = rt * 16 + q4 * 4 + rg;
        if (t < nr) {
          int gi = (r0 + t) * DM + d;
          hbuf[gi] = hbuf[gi] + a1[rt][rg] + a2[rt][rg] * LO_INV + bias;
        }
      }
  }
}

__global__ void vqvae_zero(float* __restrict__ ws) {
  int i = blockIdx.x * blockDim.x + threadIdx.x;
  if (i < 1025) ws[i] = 0.f;
}

// LDS (161,216 B) limits to 1 block/CU = 8 waves = 2 waves/SIMD.
__global__ __attribute__((amdgpu_flat_work_group_size(512, 512), amdgpu_waves_per_eu(2)))
void vqvae_main(
    const float* __restrict__ x, const float* __restrict__ W_in,
    const float* __restrict__ b_in, const float* __restrict__ cls_token,
    const float* __restrict__ Wqkv, const float* __restrict__ bqkv,
    const float* __restrict__ Wo, const float* __restrict__ bo,
    const float* __restrict__ W1, const float* __restrict__ b1,
    const float* __restrict__ W2, const float* __restrict__ b2,
    const float* __restrict__ ln1_g, const float* __restrict__ ln1_b,
    const float* __restrict__ ln2_g, const float* __restrict__ ln2_b,
    const float* __restrict__ lnf_g, const float* __restrict__ lnf_b,
    const float* __restrict__ W_out, const float* __restrict__ b_out,
    const float* __restrict__ codebook, const float* __restrict__ Wd1,
    const float* __restrict__ bd1, const float* __restrict__ lnd_g,
    const float* __restrict__ lnd_b, const float* __restrict__ Wd2,
    const float* __restrict__ bd2, const float* __restrict__ Wd3,
    const float* __restrict__ bd3, float* __restrict__ out,
    float* __restrict__ ws) {
  // 161,216 B static LDS (gfx950: 163,840 B available)
  __shared__ __align__(16) float hbuf[TT * DM];  // residual stream; later: codebook chunk [128][129]
  __shared__ __align__(16) float obuf[16896];    // x-stage [64][160] / attn-out [65][256] / FF f1 [<=33][512]
  __shared__ __align__(16) float scr[6768];      // split-fp16 staging | qkv col-major [96][65] + p rows | VQ partials

  const int tid = threadIdx.x;
  const int b = blockIdx.x;
  const int lane = tid & 63, wave = tid >> 6;
  const int q4 = lane >> 4, cl = lane & 15;
  _Float16* stg = (_Float16*)scr;
  const f32x4 Z4 = {0.f, 0.f, 0.f, 0.f};

  // ---------------- embed: h[0]=cls, h[1+r] = x[r] @ W_in^T + b_in + PE[r] ----------------
  for (int f = tid; f < SEQ * 160; f += NT) {  // stage x[b], pitch 160, zero-pad cols 142..159
    int r = f / 160, c = f - r * 160;
    obuf[f] = (c < CIN) ? x[(size_t)b * (SEQ * CIN) + r * CIN + c] : 0.f;
  }
  if (tid < DM) hbuf[tid] = cls_token[tid];

  for (int oc = 0; oc < 2; ++oc) {
    f32x4 a1[4], a2[4];
#pragma unroll
    for (int i = 0; i < 4; ++i) { a1[i] = Z4; a2[i] = Z4; }
    mfma_gemm<4, 8>(a1, a2, W_in, CIN, oc * 128, 32, 128,
                    obuf, 160, SEQ, 160, CIN, stg, tid, wave, lane);
    int d = oc * 128 + wave * 16 + cl;
    float div = expf(-(float)(d & ~1) * (9.210340371976184f / 256.0f));
    float bi = b_in[d];
#pragma unroll
    for (int rt = 0; rt < 4; ++rt)
#pragma unroll
      for (int rg = 0; rg < 4; ++rg) {
        int t = rt * 16 + q4 * 4 + rg;  // 0..63, all valid
        float ang = (float)t * div;
        float pe = (d & 1) ? cosf(ang) : sinf(ang);
        hbuf[(t + 1) * DM + d] = a1[rt][rg] + a2[rt][rg] * LO_INV + bi + pe;
      }
  }
  __syncthreads();

  // ---------------- transformer layers ----------------
  for (int li = 0; li < NL; ++li) {
    const float* Wqkv_l = Wqkv + (size_t)li * 768 * DM;
    const float* bqkv_l = bqkv + li * 768;
    const float* Wo_l = Wo + (size_t)li * DM * DM;
    const float* bo_l = bo + li * DM;
    const float* W1_l = W1 + (size_t)li * FFD * DM;
    const float* b1_l = b1 + li * FFD;
    const float* W2_l = W2 + (size_t)li * DM * FFD;
    const float* b2_l = b2 + li * DM;

    // ---- attention (per head): qkv MFMA-GEMM -> col-major scr, online softmax, o -> obuf ----
    for (int hd = 0; hd < NH; ++hd) {
      f32x4 a1[5], a2[5];
#pragma unroll
      for (int i = 0; i < 5; ++i) { a1[i] = Z4; a2[i] = Z4; }
      // O=96 (q|k|v dims of head hd): rsel=256 gathers rows {hd*32+j, 256+hd*32+j, 512+hd*32+j}
      mfma_gemm<5, 6>(a1, a2, Wqkv_l, DM, hd * 32, 256, 96,
                      hbuf, DM, TT, DM, DM, stg, tid, wave, lane);
      __syncthreads();  // all staging reads done before qkv overwrites scr
      if (wave < 6) {
        int c = wave * 16 + cl;  // 0..95: q d=c | k d=c-32 | v d=c-64
        float bias = bqkv_l[(c >> 5) * 256 + hd * 32 + (c & 31)];
#pragma unroll
        for (int rt = 0; rt < 5; ++rt)
#pragma unroll
          for (int rg = 0; rg < 4; ++rg) {
            int t = rt * 16 + q4 * 4 + rg;
            if (t < TT) scr[c * TT + t] = a1[rt][rg] + a2[rt][rg] * LO_INV + bias;
          }
      }
      __syncthreads();

      // scores: lane=u(0..63), rows t = wave+8*it; u=64 handled via reduced partial
      float sv[9];
#pragma unroll
      for (int it = 0; it < 9; ++it) sv[it] = 0.f;
#pragma unroll 4
      for (int j = 0; j < 32; ++j) {
        float kv = scr[(32 + j) * TT + lane];  // k[lane][j]
#pragma unroll
        for (int it = 0; it < 9; ++it) {
          int t = wave + 8 * it;
          if (it < 8 || t < TT) sv[it] += scr[j * TT + t] * kv;  // q[t][j] broadcast
        }
      }
#pragma unroll
      for (int it = 0; it < 9; ++it) {
        int t = wave + 8 * it;
        if (t < TT) {  // wave-uniform guard
          int jj = lane & 31;
          float p64 = scr[jj * TT + t] * scr[(32 + jj) * TT + 64] * 0.5f;  // halves dup -> *0.5
          p64 = wave_bsum(p64);
          const float sc = 0.17677669529663687f;  // 1/sqrt(32)
          float s = sv[it] * sc, s64 = p64 * sc;
          float m = fmaxf(wave_bmax(s), s64);
          float e = expf(s - m), e64 = expf(s64 - m);
          float inv = 1.0f / (wave_bsum(e) + e64);
          float* prow = &scr[96 * TT + wave * 66];
          prow[lane] = e * inv;
          if (lane == 0) prow[64] = e64 * inv;
          // o[t][e] = sum_u p[u] * v[u][e]; lanes (e, u-half)
          int e_ = lane & 31, half = lane >> 5;
          float o = 0.f;
          int u0 = half * 33, u1 = half ? 65 : 33;
#pragma unroll 4
          for (int u = u0; u < u1; ++u) o += prow[u] * scr[(64 + e_) * TT + u];
          o += __shfl_down(o, 32, 64);
          if (lane < 32) obuf[t * DM + hd * 32 + e_] = o;
        }
      }
      __syncthreads();  // before next head re-stages scr
    }

    // ---- proj + residual: h += o @ Wo^T + bo (2 x 128-col MFMA passes); LN1 ----
    for (int oc = 0; oc < 2; ++oc) {
      f32x4 a1[5], a2[5];
#pragma unroll
      for (int i = 0; i < 5; ++i) { a1[i] = Z4; a2[i] = Z4; }
      mfma_gemm<5, 8>(a1, a2, Wo_l, DM, oc * 128, 32, 128,
                      obuf, DM, TT, DM, DM, stg, tid, wave, lane);
      int d = oc * 128 + wave * 16 + cl;
      float bias = bo_l[d];
#pragma unroll
      for (int rt = 0; rt < 5; ++rt)
#pragma unroll
        for (int rg = 0; rg < 4; ++rg) {
          int t = rt * 16 + q4 * 4 + rg;
          if (t < TT) hbuf[t * DM + d] += a1[rt][rg] + a2[rt][rg] * LO_INV + bias;
        }
    }
    __syncthreads();
    ln_rows(hbuf, ln1_g + li * DM, ln1_b + li * DM, wave, lane);
    __syncthreads();

    // ---- FF: T-split two-pass (f1 storage bound) ----
    ff_block<2>(0, 32, W1_l, b1_l, W2_l, b2_l, hbuf, obuf, stg, tid, wave, lane);
    ff_block<3>(32, 33, W1_l, b1_l, W2_l, b2_l, hbuf, obuf, stg, tid, wave, lane);
    __syncthreads();
    ln_rows(hbuf, ln2_g + li * DM, ln2_b + li * DM, wave, lane);
    __syncthreads();
  }

  // ---------------- head: lnf(cls) -> z_e -> VQ argmin -> decoder (exact fp32) ----------------
  if (tid < 64) {  // lnf on row 0 -> obuf[0..255]
    float v0 = hbuf[lane], v1 = hbuf[lane + 64], v2 = hbuf[lane + 128], v3 = hbuf[lane + 192];
    float m = wave_bsum(v0 + v1 + v2 + v3) * (1.0f / 256.0f);
    float d0 = v0 - m, d1 = v1 - m, d2 = v2 - m, d3 = v3 - m;
    float var = wave_bsum(d0 * d0 + d1 * d1 + d2 * d2 + d3 * d3) * (1.0f / 256.0f);
    float rstd = 1.0f / sqrtf(var + 1e-5f);
    obuf[lane]       = d0 * rstd * lnf_g[lane]       + lnf_b[lane];
    obuf[lane + 64]  = d1 * rstd * lnf_g[lane + 64]  + lnf_b[lane + 64];
    obuf[lane + 128] = d2 * rstd * lnf_g[lane + 128] + lnf_b[lane + 128];
    obuf[lane + 192] = d3 * rstd * lnf_g[lane + 192] + lnf_b[lane + 192];
  }
  __syncthreads();
  // z_e = lnf(cls) @ W_out^T + b_out -> obuf[256..384)
  for (int o = wave; o < ED; o += 8) {
    const float4 w4 = *(const float4*)&W_out[o * DM + lane * 4];
    const float4 c4 = *(const float4*)&obuf[lane * 4];
    float s = w4.x * c4.x + w4.y * c4.y + w4.z * c4.z + w4.w * c4.w;
    s = wave_bsum(s);
    if (lane == 0) obuf[256 + o] = s + b_out[o];
  }
  __syncthreads();

  // VQ argmin over |cb|^2 - 2 ze.cb (|ze|^2 constant); first-index tie-break
  float bestv = 3.4e38f;
  int bestk = 0;
  for (int ch = 0; ch < 8; ++ch) {
    __syncthreads();
    for (int f = tid; f < 128 * 128; f += NT) {  // stage cb chunk, rows padded to 129
      int r = f >> 7, c = f & 127;
      hbuf[r * 129 + c] = codebook[(size_t)(ch * 128 + r) * ED + c];
    }
    __syncthreads();
    {
      int kl = tid & 127, q = tid >> 7;
      float part = 0.f;
#pragma unroll 8
      for (int jj = 0; jj < 32; ++jj) {
        int e = q * 32 + jj;
        float cv = hbuf[kl * 129 + e];
        part += cv * (cv - 2.0f * obuf[256 + e]);
      }
      scr[kl * 4 + q] = part;
    }
    __syncthreads();
    if (tid < 128) {
      float d2v = scr[tid * 4] + scr[tid * 4 + 1] + scr[tid * 4 + 2] + scr[tid * 4 + 3];
      int kk = ch * 128 + tid;
      if (d2v < bestv) { bestv = d2v; bestk = kk; }  // ascending k per thread
    }
  }
  if (tid < 128) {
    scr[512 + tid] = bestv;
    scr[640 + tid] = __int_as_float(bestk);
  }
  __syncthreads();
  if (tid == 0) {
    float bv = 3.4e38f;
    int bk = 1 << 30;
    for (int j = 0; j < 128; ++j) {
      float v = scr[512 + j];
      int kk = __float_as_int(scr[640 + j]);
      if (v < bv || (v == bv && kk < bk)) { bv = v; bk = kk; }
    }
    scr[700] = __int_as_float(bk);
    out[2 * NB + b] = (float)bk;  // indices output (as float value)
  }
  __syncthreads();
  const int bk = __float_as_int(scr[700]);

  // z_q -> obuf[384..512); commitment + histogram
  if (tid < ED) {
    float zqv = codebook[(size_t)bk * ED + tid];
    obuf[384 + tid] = zqv;
    float df = zqv - obuf[256 + tid];
    float sq = wave_bsum(df * df);
    if ((tid & 63) == 0) atomicAdd(&ws[0], sq);
  }
  if (tid == 0) atomicAdd(&ws[1 + bk], 1.0f);
  __syncthreads();

  // decoder: d1 = zq @ Wd1^T + bd1 (256) -> LN -> gelu -> @Wd2^T (128) -> gelu -> @Wd3^T (2)
  for (int o = wave; o < DM; o += 8) {
    const float2 w2 = *(const float2*)&Wd1[o * ED + lane * 2];
    const float2 z2 = *(const float2*)&obuf[384 + lane * 2];
    float s = wave_bsum(w2.x * z2.x + w2.y * z2.y);
    if (lane == 0) obuf[512 + o] = s + bd1[o];
  }
  __syncthreads();
  if (tid < 64) {
    float v0 = obuf[512 + lane], v1 = obuf[512 + lane + 64];
    float v2 = obuf[512 + lane + 128], v3 = obuf[512 + lane + 192];
    float m = wave_bsum(v0 + v1 + v2 + v3) * (1.0f / 256.0f);
    float d0 = v0 - m, d1 = v1 - m, d2 = v2 - m, d3 = v3 - m;
    float var = wave_bsum(d0 * d0 + d1 * d1 + d2 * d2 + d3 * d3) * (1.0f / 256.0f);
    float rstd = 1.0f / sqrtf(var + 1e-5f);
    obuf[512 + lane]       = gelu_f(d0 * rstd * lnd_g[lane]       + lnd_b[lane]);
    obuf[512 + lane + 64]  = gelu_f(d1 * rstd * lnd_g[lane + 64]  + lnd_b[lane + 64]);
    obuf[512 + lane + 128] = gelu_f(d2 * rstd * lnd_g[lane + 128] + lnd_b[lane + 128]);
    obuf[512 + lane + 192] = gelu_f(d3 * rstd * lnd_g[lane + 192] + lnd_b[lane + 192]);
  }
  __syncthreads();
  for (int o = wave; o < ED; o += 8) {
    const float4 w4 = *(const float4*)&Wd2[o * DM + lane * 4];
    const float4 g4 = *(const float4*)&obuf[512 + lane * 4];
    float s = wave_bsum(w4.x * g4.x + w4.y * g4.y + w4.z * g4.z + w4.w * g4.w);
    if (lane == 0) obuf[768 + o] = gelu_f(s + bd2[o]);
  }
  __syncthreads();
  if (wave < 2) {
    const float2 w2 = *(const float2*)&Wd3[wave * ED + lane * 2];
    const float2 g2 = *(const float2*)&obuf[768 + lane * 2];
    float s = wave_bsum(w2.x * g2.x + w2.y * g2.y);
    if (lane == 0) out[b * 2 + wave] = s + bd3[wave];
  }
}

__global__ void vqvae_finish(const float* __restrict__ ws, float* __restrict__ out) {
  __shared__ float red[256];
  int tid = threadIdx.x;
  float part = 0.f;
  for (int k = tid; k < KCB; k += 256) {
    float p = ws[1 + k] * (1.0f / 2048.0f);
    part += p * logf(p + 1e-10f);
  }
  red[tid] = part;
  __syncthreads();
  for (int s = 128; s > 0; s >>= 1) {
    if (tid < s) red[tid] += red[tid + s];
    __syncthreads();
  }
  if (tid == 0) {
    out[2 * NB + NB]     = 0.1f * ws[0] * (1.0f / (2048.0f * 128.0f));  // commitment loss
    out[2 * NB + NB + 1] = expf(-red[0]);                               // perplexity
  }
}

extern "C" void kernel_launch(void* const* d_in, const int* in_sizes, int n_in,
                              void* d_out, int out_size, void* d_ws, size_t ws_size,
                              hipStream_t stream) {
  (void)in_sizes; (void)n_in; (void)out_size; (void)ws_size;
  const float* x         = (const float*)d_in[0];
  const float* W_in      = (const float*)d_in[1];
  const float* b_in      = (const float*)d_in[2];
  const float* cls_token = (const float*)d_in[3];
  const float* Wqkv      = (const float*)d_in[4];
  const float* bqkv      = (const float*)d_in[5];
  const float* Wo        = (const float*)d_in[6];
  const float* bo        = (const float*)d_in[7];
  const float* W1        = (const float*)d_in[8];
  const float* b1        = (const float*)d_in[9];
  const float* W2        = (const float*)d_in[10];
  const float* b2        = (const float*)d_in[11];
  const float* ln1_g     = (const float*)d_in[12];
  const float* ln1_b     = (const float*)d_in[13];
  const float* ln2_g     = (const float*)d_in[14];
  const float* ln2_b     = (const float*)d_in[15];
  const float* lnf_g     = (const float*)d_in[16];
  const float* lnf_b     = (const float*)d_in[17];
  const float* W_out     = (const float*)d_in[18];
  const float* b_out     = (const float*)d_in[19];
  const float* codebook  = (const float*)d_in[20];
  const float* Wd1       = (const float*)d_in[21];
  const float* bd1       = (const float*)d_in[22];
  const float* lnd_g     = (const float*)d_in[23];
  const float* lnd_b     = (const float*)d_in[24];
  const float* Wd2       = (const float*)d_in[25];
  const float* bd2       = (const float*)d_in[26];
  const float* Wd3       = (const float*)d_in[27];
  const float* bd3       = (const float*)d_in[28];
  float* out = (float*)d_out;
  float* ws = (float*)d_ws;

  hipLaunchKernelGGL(vqvae_zero, dim3(5), dim3(256), 0, stream, ws);
  hipLaunchKernelGGL(vqvae_main, dim3(NB), dim3(NT), 0, stream,
                     x, W_in, b_in, cls_token, Wqkv, bqkv, Wo, bo, W1, b1, W2, b2,
                     ln1_g, ln1_b, ln2_g, ln2_b, lnf_g, lnf_b, W_out, b_out,
                     codebook, Wd1, bd1, lnd_g, lnd_b, Wd2, bd2, Wd3, bd3, out, ws);
  hipLaunchKernelGGL(vqvae_finish, dim3(1), dim3(256), 0, stream, ws, out);
}